// Round 1
// baseline (458.043 us; speedup 1.0000x reference)
//
#include <hip/hip_runtime.h>
#include <math.h>

#define NPTS 65536

using half8   = __attribute__((ext_vector_type(8))) _Float16;
using floatx4 = __attribute__((ext_vector_type(4))) float;

// ---------------------------------------------------------------------------
// k_prep: cast+transpose weights to f16 B-operand layout [64 cols][960 kc]
//   owt[d][kc] = offset_weight[k][c][d]  (d>=60 -> 0)
//   wt [o][kc] = weight[k][c][o]
// ---------------------------------------------------------------------------
__global__ __launch_bounds__(256) void k_prep(
    const float* __restrict__ ow, const float* __restrict__ w,
    _Float16* __restrict__ owt, _Float16* __restrict__ wt)
{
  int i = blockIdx.x * 256 + threadIdx.x;
  if (i >= 61440) return;           // 64 * 960
  int d = i / 960, kc = i - d * 960;
  owt[i] = (d < 60) ? (_Float16)ow[kc * 60 + d] : (_Float16)0.f;
  wt[i]  = (_Float16)w[kc * 64 + d];
}

// ---------------------------------------------------------------------------
// Fused KPConv (16 points per block, 4 waves x 4 points) + in-block GEMM.
// PASS 0: rigid conv -> f0 GEMM vs owt -> def_kp/modulations into dkbuf[N][64]
// PASS 1: deformable conv (def_kp, modulation) -> x GEMM vs wt -> outv[N][64]
// MFMA f32_16x16x32_f16 layouts (verified per guide):
//   A[m=lane&15][k=quad*8+j], B[k=quad*8+j][n=lane&15],
//   C/D col=lane&15, row=quad*4+reg
// ---------------------------------------------------------------------------
template <int PASS>
__global__ __launch_bounds__(256) void k_conv(
    const float* __restrict__ query, const float* __restrict__ support,
    const int* __restrict__ nidx, const float* __restrict__ feat,
    const float* __restrict__ kpts, const float* __restrict__ obias,
    const float* __restrict__ dkin,        // PASS1: def_kp+mod [N][64]
    const _Float16* __restrict__ bmat,     // owt (PASS0) / wt (PASS1)
    float* __restrict__ outv)              // PASS0: dkbuf; PASS1: x pre-BN
{
  __shared__ __align__(16) float4   npts[16][40];   // neighbor - query, pad=1e6
  __shared__ int                    sidx[16][40];
  __shared__ __align__(16) _Float16 wfh[16][1088];  // wf tile, kc at k*72+c

  const int tid  = threadIdx.x;
  const int wave = tid >> 6, lane = tid & 63;
  const int quad = lane >> 4, mm = lane & 15;
  const int base = blockIdx.x * 16;

  // cooperative staging of neighbor displacement vectors + indices
  for (int s = tid; s < 640; s += 256) {
    int pt = s / 40, a = s - pt * 40;
    int n = base + pt;
    float4 np; int id = 0;
    if (a < 34) {
      id = nidx[n * 34 + a];
      np.x = support[id * 3 + 0] - query[n * 3 + 0];
      np.y = support[id * 3 + 1] - query[n * 3 + 1];
      np.z = support[id * 3 + 2] - query[n * 3 + 2];
    } else {
      np.x = 1e6f; np.y = 1e6f; np.z = 1e6f;   // influence -> relu(neg) = 0
    }
    np.w = 0.f;
    npts[pt][a] = np;
    sidx[pt][a] = id;
  }
  __syncthreads();

  const int me = (mm < 15) ? mm : 14;   // row 15 of A is garbage-but-finite
  const floatx4 fz = {0.f, 0.f, 0.f, 0.f};

  #pragma unroll
  for (int pp = 0; pp < 4; ++pp) {
    const int pl = wave * 4 + pp;
    const int n  = base + pl;

    float kx, ky, kz;
    if (PASS == 0) {
      kx = kpts[me * 3 + 0]; ky = kpts[me * 3 + 1]; kz = kpts[me * 3 + 2];
    } else {
      const float* dk = dkin + n * 64;
      kx = dk[me * 3 + 0]; ky = dk[me * 3 + 1]; kz = dk[me * 3 + 2];
    }

    // A-frags: influence weights w[a][k] with k = mm, a = chunk*32 + quad*8 + j
    half8 a0, a1;
    #pragma unroll
    for (int j = 0; j < 8; ++j) {
      float4 p = npts[pl][quad * 8 + j];
      float dx = p.x - kx, dy = p.y - ky, dz = p.z - kz;
      float wv = 1.f - 2.f * sqrtf(dx * dx + dy * dy + dz * dz);
      a0[j] = (_Float16)fmaxf(wv, 0.f);
    }
    if (quad == 0) {
      #pragma unroll
      for (int j = 0; j < 8; ++j) {
        float4 p = npts[pl][32 + j];
        float dx = p.x - kx, dy = p.y - ky, dz = p.z - kz;
        float wv = 1.f - 2.f * sqrtf(dx * dx + dy * dy + dz * dz);
        a1[j] = (_Float16)fmaxf(wv, 0.f);
      }
    } else {
      #pragma unroll
      for (int j = 0; j < 8; ++j) a1[j] = (_Float16)0.f;
    }

    int id0[8];
    #pragma unroll
    for (int j = 0; j < 8; ++j) id0[j] = sidx[pl][quad * 8 + j];

    floatx4 acc[4];
    #pragma unroll
    for (int ct = 0; ct < 4; ++ct) {
      const int c = ct * 16 + mm;
      half8 b;
      #pragma unroll
      for (int j = 0; j < 8; ++j) b[j] = (_Float16)feat[id0[j] * 64 + c];
      acc[ct] = __builtin_amdgcn_mfma_f32_16x16x32_f16(a0, b, fz, 0, 0, 0);
    }
    int id1[8];
    #pragma unroll
    for (int j = 0; j < 8; ++j) id1[j] = (quad == 0) ? sidx[pl][32 + j] : 0;
    #pragma unroll
    for (int ct = 0; ct < 4; ++ct) {
      const int c = ct * 16 + mm;
      half8 b;
      if (quad == 0) {
        #pragma unroll
        for (int j = 0; j < 8; ++j) b[j] = (_Float16)feat[id1[j] * 64 + c];
      } else {
        #pragma unroll
        for (int j = 0; j < 8; ++j) b[j] = (_Float16)0.f;
      }
      acc[ct] = __builtin_amdgcn_mfma_f32_16x16x32_f16(a1, b, acc[ct], 0, 0, 0);
    }

    float md[4];
    #pragma unroll
    for (int r = 0; r < 4; ++r) {
      int k = quad * 4 + r;
      md[r] = (PASS == 1 && k < 15) ? dkin[n * 64 + 45 + k] : 1.f;
    }
    #pragma unroll
    for (int ct = 0; ct < 4; ++ct)
      #pragma unroll
      for (int r = 0; r < 4; ++r) {
        int k = quad * 4 + r;
        if (k < 15) wfh[pl][k * 72 + ct * 16 + mm] = (_Float16)(acc[ct][r] * md[r]);
      }
  }
  __syncthreads();

  // In-block GEMM: [16 pts][960] @ bmat^T[64][960]; wave owns col-tile ct=wave
  floatx4 accA = fz, accB = fz;
  const int ct = wave;
  const int d  = ct * 16 + mm;
  const _Float16* brow = bmat + d * 960;
  #pragma unroll
  for (int k2 = 0; k2 < 30; ++k2) {
    int kc2  = k2 * 32;
    int phys = (k2 >> 1) * 72 + (k2 & 1) * 32;
    half8 af = *(const half8*)(&wfh[mm][phys + quad * 8]);
    half8 bf = *(const half8*)(brow + kc2 + quad * 8);
    if (k2 & 1) accB = __builtin_amdgcn_mfma_f32_16x16x32_f16(af, bf, accB, 0, 0, 0);
    else        accA = __builtin_amdgcn_mfma_f32_16x16x32_f16(af, bf, accA, 0, 0, 0);
  }

  float bv = 0.f, kv = 0.f;
  if (PASS == 0) {
    bv = (d < 60) ? obias[d] : 0.f;
    kv = (d < 45) ? kpts[d] : 0.f;
  }
  #pragma unroll
  for (int r = 0; r < 4; ++r) {
    const int n = base + quad * 4 + r;
    float v = accA[r] + accB[r];
    if (PASS == 0) {
      v += bv;
      float o = (d < 45) ? (kv + 0.5f * v)               // def_kp = kp + f0*EXTENT
                         : (2.f / (1.f + expf(-v)));     // modulation = 2*sigmoid
      outv[n * 64 + d] = o;
    } else {
      outv[n * 64 + d] = v;
    }
  }
}

// ---------------------------------------------------------------------------
// Per-channel batch stats: stats[0..63]=sum, stats[64..127]=sumsq
// ---------------------------------------------------------------------------
__global__ __launch_bounds__(256) void k_stats(
    const float* __restrict__ x, float* __restrict__ stats)
{
  __shared__ float red[512];
  const int tid = threadIdx.x;
  const int c = tid & 63, g = tid >> 6;
  float s1 = 0.f, s2 = 0.f;
  for (int r = blockIdx.x * 4 + g; r < NPTS; r += 1024) {
    float v = x[r * 64 + c];
    s1 += v; s2 += v * v;
  }
  red[tid] = s1; red[256 + tid] = s2;
  __syncthreads();
  if (tid < 64) {
    s1 = red[tid] + red[tid + 64] + red[tid + 128] + red[tid + 192];
    s2 = red[256 + tid] + red[256 + tid + 64] + red[256 + tid + 128] + red[256 + tid + 192];
    atomicAdd(&stats[c], s1);
    atomicAdd(&stats[64 + c], s2);
  }
}

// ---------------------------------------------------------------------------
// BN (training-mode batch stats, biased var) + LeakyReLU(0.1), in-place
// ---------------------------------------------------------------------------
__global__ __launch_bounds__(256) void k_norm(
    float* __restrict__ x, const float* __restrict__ stats,
    const float* __restrict__ gamma, const float* __restrict__ beta)
{
  const int i = blockIdx.x * 256 + threadIdx.x;
  float4 v = ((float4*)x)[i];
  const int c0 = (i * 4) & 63;
  float o[4] = {v.x, v.y, v.z, v.w};
  #pragma unroll
  for (int j = 0; j < 4; ++j) {
    int c = c0 + j;
    float mean = stats[c] * (1.f / NPTS);
    float var  = stats[64 + c] * (1.f / NPTS) - mean * mean;
    float s = rsqrtf(var + 1e-6f) * gamma[c];
    float y = (o[j] - mean) * s + beta[c];
    o[j] = (y >= 0.f) ? y : 0.1f * y;
  }
  float4 rv = {o[0], o[1], o[2], o[3]};
  ((float4*)x)[i] = rv;
}

// ---------------------------------------------------------------------------
extern "C" void kernel_launch(void* const* d_in, const int* in_sizes, int n_in,
                              void* d_out, int out_size, void* d_ws, size_t ws_size,
                              hipStream_t stream)
{
  const float* query   = (const float*)d_in[0];
  const float* support = (const float*)d_in[1];
  const int*   nidx    = (const int*)d_in[2];
  const float* feat    = (const float*)d_in[3];
  const float* weight  = (const float*)d_in[4];
  const float* oweight = (const float*)d_in[5];
  const float* obias   = (const float*)d_in[6];
  const float* gamma   = (const float*)d_in[7];
  const float* beta    = (const float*)d_in[8];
  const float* kpts    = (const float*)d_in[9];
  float* x = (float*)d_out;

  char* ws = (char*)d_ws;
  float*    dkbuf = (float*)ws;                    // 16,777,216 B
  _Float16* owt   = (_Float16*)(ws + 16777216);    //    122,880 B
  _Float16* wt    = (_Float16*)(ws + 16900096);    //    122,880 B
  float*    stats = (float*)(ws + 17022976);       //        512 B

  hipMemsetAsync(stats, 0, 512, stream);
  k_prep<<<240, 256, 0, stream>>>(oweight, weight, owt, wt);
  k_conv<0><<<4096, 256, 0, stream>>>(query, support, nidx, feat, kpts, obias,
                                      nullptr, owt, dkbuf);
  k_conv<1><<<4096, 256, 0, stream>>>(query, support, nidx, feat, kpts, obias,
                                      dkbuf, wt, x);
  k_stats<<<256, 256, 0, stream>>>(x, stats);
  k_norm<<<4096, 256, 0, stream>>>(x, stats, gamma, beta);
}

// Round 2
// 403.106 us; speedup vs baseline: 1.1363x; 1.1363x over previous
//
#include <hip/hip_runtime.h>
#include <math.h>

#define NPTS 65536

using half8   = __attribute__((ext_vector_type(8))) _Float16;
using half4   = __attribute__((ext_vector_type(4))) _Float16;
using floatx4 = __attribute__((ext_vector_type(4))) float;

// ---------------------------------------------------------------------------
// k_prep: weights -> f16 transposed [64 d][960 kc] (kc = k*64 + c);
//         features -> f16 table featH[N][64]
// ---------------------------------------------------------------------------
__global__ __launch_bounds__(256) void k_prep(
    const float* __restrict__ ow, const float* __restrict__ w,
    const float* __restrict__ feat,
    _Float16* __restrict__ owt, _Float16* __restrict__ wt,
    _Float16* __restrict__ featH)
{
  int b = blockIdx.x;
  if (b < 240) {                       // 240*256 == 61440 == 64*960
    int i = b * 256 + threadIdx.x;
    int d = i / 960, kc = i - d * 960;
    owt[i] = (d < 60) ? (_Float16)ow[kc * 60 + d] : (_Float16)0.f;
    wt[i]  = (_Float16)w[kc * 64 + d];
  } else {                             // 4096*256 == 1048576 == N*64/4
    int j = (b - 240) * 256 + threadIdx.x;
    float4 f = ((const float4*)feat)[j];
    half4 h = {(_Float16)f.x, (_Float16)f.y, (_Float16)f.z, (_Float16)f.w};
    ((half4*)featH)[j] = h;
  }
}

// ---------------------------------------------------------------------------
// Fused deformable KPConv block: conv0 -> GEMM0(owt) -> def_kp/mod (LDS) ->
// conv1 -> GEMM1(wt) -> x (pre-BN). 16 points/block, 4 waves x 4 points.
// fT[c][a] swizzled: physical a-chunk = chunk ^ ((c>>3)^(c&7)&7)
// ---------------------------------------------------------------------------
__global__ __launch_bounds__(256, 2) void k_fused(
    const float* __restrict__ query, const float* __restrict__ support,
    const int* __restrict__ nidx, const _Float16* __restrict__ featH,
    const float* __restrict__ kpts, const float* __restrict__ obias,
    const _Float16* __restrict__ owt, const _Float16* __restrict__ wt,
    float* __restrict__ outx)
{
  __shared__ __align__(16) float4   npts[16][40];   // neighbor - query (w unused)
  __shared__ int                    sidx[16][40];
  __shared__ __align__(16) _Float16 fT[4][64 * 64]; // per-wave transposed feats
  __shared__ __align__(16) _Float16 wfh[16 * 968];  // [pt][kc], row pad 960->968
  __shared__ float                  dk[16][68];     // def_kp(45)+mod(15), pad 68

  const int tid  = threadIdx.x;
  const int wave = tid >> 6, lane = tid & 63;
  const int quad = lane >> 4, mm = lane & 15;
  const int base = blockIdx.x * 16;
  _Float16* fTw = fT[wave];
  const floatx4 fz = {0.f, 0.f, 0.f, 0.f};
  const int me = (mm < 15) ? mm : 14;   // row 15 of conv A is discarded

  // ---- stage neighbor displacements + indices ----
  for (int s = tid; s < 640; s += 256) {
    int pt = s / 40, a = s - pt * 40;
    int n = base + pt;
    float4 np = {1e6f, 1e6f, 1e6f, 0.f};
    int id = 0;
    if (a < 34) {
      id = nidx[n * 34 + a];
      np.x = support[id * 3 + 0] - query[n * 3 + 0];
      np.y = support[id * 3 + 1] - query[n * 3 + 1];
      np.z = support[id * 3 + 2] - query[n * 3 + 2];
    }
    npts[pt][a] = np;
    sidx[pt][a] = id;
  }
  // ---- zero fT logical chunks 5..7 (a=40..63), per wave, once ----
  {
    int X = ((lane >> 3) ^ (lane & 7)) & 7;
    half8 z8 = {0, 0, 0, 0, 0, 0, 0, 0};
    #pragma unroll
    for (int i = 0; i < 3; ++i)
      *(half8*)(fTw + lane * 64 + (((5 + i) ^ X) << 3)) = z8;
  }
  __syncthreads();

  // ---- gather: transpose point pl's 40 neighbor feature rows into fTw ----
  auto gather = [&](int pl) {
    uint4 g0[3], g1[3];
    #pragma unroll
    for (int it = 0; it < 3; ++it) {
      int task = it * 64 + lane;
      if (task < 160) {
        int rp = task >> 3, ch = task & 7;
        int i0 = sidx[pl][2 * rp], i1 = sidx[pl][2 * rp + 1];
        g0[it] = *(const uint4*)(featH + i0 * 64 + ch * 8);
        g1[it] = *(const uint4*)(featH + i1 * 64 + ch * 8);
      }
    }
    #pragma unroll
    for (int it = 0; it < 3; ++it) {
      int task = it * 64 + lane;
      if (task < 160) {
        int rp = task >> 3, ch = task & 7;
        const uint* p0 = (const uint*)&g0[it];
        const uint* p1 = (const uint*)&g1[it];
        #pragma unroll
        for (int cc = 0; cc < 8; ++cc) {
          int c = ch * 8 + cc;
          int X = (ch ^ cc) & 7;
          int ap = (2 * rp) ^ (X << 3);
          uint v = __builtin_amdgcn_perm(p1[cc >> 1], p0[cc >> 1],
                                         (cc & 1) ? 0x07060302u : 0x05040100u);
          *(uint*)(fTw + c * 64 + ap) = v;
        }
      }
    }
  };

  // ---- one conv point: influence A-frags + 8 MFMA -> wfh[pl] ----
  auto conv_point = [&](int pl, float kx, float ky, float kz, const float* md) {
    half8 a0, a1;
    #pragma unroll
    for (int j = 0; j < 8; ++j) {
      float4 p = npts[pl][quad * 8 + j];
      float dx = p.x - kx, dy = p.y - ky, dz = p.z - kz;
      float wv = 1.f - 2.f * sqrtf(dx * dx + dy * dy + dz * dz);
      a0[j] = (_Float16)fmaxf(wv, 0.f);
    }
    if (quad == 0) {
      #pragma unroll
      for (int j = 0; j < 8; ++j) {
        float4 p = npts[pl][32 + j];
        float dx = p.x - kx, dy = p.y - ky, dz = p.z - kz;
        float wv = 1.f - 2.f * sqrtf(dx * dx + dy * dy + dz * dz);
        a1[j] = (_Float16)fmaxf(wv, 0.f);
      }
    } else {
      #pragma unroll
      for (int j = 0; j < 8; ++j) a1[j] = (_Float16)0.f;
    }

    floatx4 acc[4];
    #pragma unroll
    for (int ct = 0; ct < 4; ++ct) {
      int c = ct * 16 + mm;
      int X = (((c >> 3) ^ (c & 7)) & 7);
      half8 b = *(const half8*)(fTw + c * 64 + ((quad ^ X) << 3));
      acc[ct] = __builtin_amdgcn_mfma_f32_16x16x32_f16(a0, b, fz, 0, 0, 0);
    }
    #pragma unroll
    for (int ct = 0; ct < 4; ++ct) {
      int c = ct * 16 + mm;
      int X = (((c >> 3) ^ (c & 7)) & 7);
      half8 b = *(const half8*)(fTw + c * 64 + (((4 + quad) ^ X) << 3));
      acc[ct] = __builtin_amdgcn_mfma_f32_16x16x32_f16(a1, b, acc[ct], 0, 0, 0);
    }

    _Float16* wp = wfh + pl * 968;
    #pragma unroll
    for (int ct = 0; ct < 4; ++ct)
      #pragma unroll
      for (int r = 0; r < 4; ++r) {
        int k = quad * 4 + r;
        if (k < 15) wp[k * 64 + ct * 16 + mm] = (_Float16)(acc[ct][r] * md[r]);
      }
  };

  // ---- block GEMM: [16 pts][960] x bmat[64][960]^T, wave owns 16 cols ----
  auto gemm = [&](const _Float16* bmat, floatx4& A, floatx4& B) {
    const _Float16* brow = bmat + (wave * 16 + mm) * 960;
    const _Float16* arow = wfh + mm * 968;
    A = fz; B = fz;
    #pragma unroll
    for (int k2 = 0; k2 < 30; ++k2) {
      half8 af = *(const half8*)(arow + k2 * 32 + quad * 8);
      half8 bf = *(const half8*)(brow + k2 * 32 + quad * 8);
      if (k2 & 1) B = __builtin_amdgcn_mfma_f32_16x16x32_f16(af, bf, B, 0, 0, 0);
      else        A = __builtin_amdgcn_mfma_f32_16x16x32_f16(af, bf, A, 0, 0, 0);
    }
  };

  // ================= conv0 (rigid kernel points) =================
  {
    float k0x = kpts[me * 3 + 0], k0y = kpts[me * 3 + 1], k0z = kpts[me * 3 + 2];
    float one4[4] = {1.f, 1.f, 1.f, 1.f};
    for (int pp = 0; pp < 4; ++pp) {
      int pl = wave * 4 + pp;
      gather(pl);
      conv_point(pl, k0x, k0y, k0z, one4);
    }
  }
  __syncthreads();

  // ================= GEMM0 -> def_kp + modulations =================
  {
    floatx4 A, B;
    gemm(owt, A, B);
    int d = wave * 16 + mm;
    float bv = (d < 60) ? obias[d] : 0.f;
    float kv = (d < 45) ? kpts[d] : 0.f;
    #pragma unroll
    for (int r = 0; r < 4; ++r) {
      int pt = quad * 4 + r;
      float v = A[r] + B[r] + bv;
      float o = (d < 45) ? (kv + 0.5f * v)            // def_kp = kp + f0*EXTENT
                         : (2.f / (1.f + expf(-v)));  // modulation
      dk[pt][d] = o;
    }
  }
  __syncthreads();   // dk ready; all GEMM0 wfh reads done

  // ================= conv1 (deformed kernel points) =================
  for (int pp = 0; pp < 4; ++pp) {
    int pl = wave * 4 + pp;
    gather(pl);
    float kx = dk[pl][me * 3 + 0], ky = dk[pl][me * 3 + 1], kz = dk[pl][me * 3 + 2];
    float md[4];
    #pragma unroll
    for (int r = 0; r < 4; ++r) {
      int k = quad * 4 + r;
      md[r] = (k < 15) ? dk[pl][45 + k] : 1.f;
    }
    conv_point(pl, kx, ky, kz, md);
  }
  __syncthreads();

  // ================= GEMM1 -> x (pre-BN) =================
  {
    floatx4 A, B;
    gemm(wt, A, B);
    int d = wave * 16 + mm;
    #pragma unroll
    for (int r = 0; r < 4; ++r)
      outx[(base + quad * 4 + r) * 64 + d] = A[r] + B[r];
  }
}

// ---------------------------------------------------------------------------
// Per-channel batch stats: stats[0..63]=sum, stats[64..127]=sumsq
// ---------------------------------------------------------------------------
__global__ __launch_bounds__(256) void k_stats(
    const float* __restrict__ x, float* __restrict__ stats)
{
  __shared__ float red[512];
  const int tid = threadIdx.x;
  const int c = tid & 63, g = tid >> 6;
  float s1 = 0.f, s2 = 0.f;
  for (int r = blockIdx.x * 4 + g; r < NPTS; r += 1024) {
    float v = x[r * 64 + c];
    s1 += v; s2 += v * v;
  }
  red[tid] = s1; red[256 + tid] = s2;
  __syncthreads();
  if (tid < 64) {
    s1 = red[tid] + red[tid + 64] + red[tid + 128] + red[tid + 192];
    s2 = red[256 + tid] + red[256 + tid + 64] + red[256 + tid + 128] + red[256 + tid + 192];
    atomicAdd(&stats[c], s1);
    atomicAdd(&stats[64 + c], s2);
  }
}

// ---------------------------------------------------------------------------
// BN (batch stats, biased var, eps=1e-6) + LeakyReLU(0.1), in-place
// ---------------------------------------------------------------------------
__global__ __launch_bounds__(256) void k_norm(
    float* __restrict__ x, const float* __restrict__ stats,
    const float* __restrict__ gamma, const float* __restrict__ beta)
{
  const int i = blockIdx.x * 256 + threadIdx.x;
  float4 v = ((float4*)x)[i];
  const int c0 = (i * 4) & 63;
  float o[4] = {v.x, v.y, v.z, v.w};
  #pragma unroll
  for (int j = 0; j < 4; ++j) {
    int c = c0 + j;
    float mean = stats[c] * (1.f / NPTS);
    float var  = stats[64 + c] * (1.f / NPTS) - mean * mean;
    float s = rsqrtf(var + 1e-6f) * gamma[c];
    float y = (o[j] - mean) * s + beta[c];
    o[j] = (y >= 0.f) ? y : 0.1f * y;
  }
  float4 rv = {o[0], o[1], o[2], o[3]};
  ((float4*)x)[i] = rv;
}

// ---------------------------------------------------------------------------
extern "C" void kernel_launch(void* const* d_in, const int* in_sizes, int n_in,
                              void* d_out, int out_size, void* d_ws, size_t ws_size,
                              hipStream_t stream)
{
  const float* query   = (const float*)d_in[0];
  const float* support = (const float*)d_in[1];
  const int*   nidx    = (const int*)d_in[2];
  const float* feat    = (const float*)d_in[3];
  const float* weight  = (const float*)d_in[4];
  const float* oweight = (const float*)d_in[5];
  const float* obias   = (const float*)d_in[6];
  const float* gamma   = (const float*)d_in[7];
  const float* beta    = (const float*)d_in[8];
  const float* kpts    = (const float*)d_in[9];
  float* x = (float*)d_out;

  char* ws = (char*)d_ws;
  _Float16* featH = (_Float16*)ws;                  // 8,388,608 B
  _Float16* owt   = (_Float16*)(ws + 8388608);      //   122,880 B
  _Float16* wt    = (_Float16*)(ws + 8511488);      //   122,880 B
  float*    stats = (float*)(ws + 8634368);         //       512 B

  hipMemsetAsync(stats, 0, 512, stream);
  k_prep<<<4336, 256, 0, stream>>>(oweight, weight, feat, owt, wt, featH);
  k_fused<<<4096, 256, 0, stream>>>(query, support, nidx, featH, kpts, obias,
                                    owt, wt, x);
  k_stats<<<256, 256, 0, stream>>>(x, stats);
  k_norm<<<4096, 256, 0, stream>>>(x, stats, gamma, beta);
}

// Round 3
// 375.224 us; speedup vs baseline: 1.2207x; 1.0743x over previous
//
#include <hip/hip_runtime.h>
#include <math.h>

#define NPTS 65536

using half8   = __attribute__((ext_vector_type(8))) _Float16;
using half4   = __attribute__((ext_vector_type(4))) _Float16;
using floatx4 = __attribute__((ext_vector_type(4))) float;

// ---------------------------------------------------------------------------
// k_prep: weights -> f16 [64 d][1024 kc'] with kc' = c*16 + k (k=15 row zero);
//         features -> f16 table featH[N][64]
// ---------------------------------------------------------------------------
__global__ __launch_bounds__(256) void k_prep(
    const float* __restrict__ ow, const float* __restrict__ w,
    const float* __restrict__ feat,
    _Float16* __restrict__ owt, _Float16* __restrict__ wt,
    _Float16* __restrict__ featH)
{
  int b = blockIdx.x;
  if (b < 256) {                       // 256*256 == 65536 == 64*1024
    int i = b * 256 + threadIdx.x;
    int d = i >> 10, kc = i & 1023, c = kc >> 4, k = kc & 15;
    owt[i] = (k < 15 && d < 60) ? (_Float16)ow[(k * 64 + c) * 60 + d] : (_Float16)0.f;
    wt[i]  = (k < 15) ? (_Float16)w[(k * 64 + c) * 64 + d] : (_Float16)0.f;
  } else {                             // 4096*256 == 1048576 == N*64/4
    int j = (b - 256) * 256 + threadIdx.x;
    float4 f = ((const float4*)feat)[j];
    half4 h = {(_Float16)f.x, (_Float16)f.y, (_Float16)f.z, (_Float16)f.w};
    ((half4*)featH)[j] = h;
  }
}

// ---------------------------------------------------------------------------
// Fused deformable KPConv block: conv0 -> GEMM0(owt) -> def_kp/mod (LDS) ->
// conv1 -> GEMM1(wt) -> x (pre-BN). 16 points/block, 4 waves x 4 points.
// fT[c][a] XOR-swizzled (chunk ^= ((c>>3)^(c&7))&7): b128 reads + dword
// writes both at bank floor. wfh[pt][c*16+k] (stride 1032): half4 writes and
// b128 GEMM A-frag reads both at floor. Gather loads double-buffered in regs.
// ---------------------------------------------------------------------------
__global__ __launch_bounds__(256, 2) void k_fused(
    const float* __restrict__ query, const float* __restrict__ support,
    const int* __restrict__ nidx, const _Float16* __restrict__ featH,
    const float* __restrict__ kpts, const float* __restrict__ obias,
    const _Float16* __restrict__ owt, const _Float16* __restrict__ wt,
    float* __restrict__ outx)
{
  __shared__ float                  npx[16][40], npy[16][40], npz[16][40];
  __shared__ unsigned short         sidx[16][40];
  __shared__ __align__(16) _Float16 fT[4][64 * 64];  // per-wave transposed feats
  __shared__ __align__(16) _Float16 wfh[16 * 1032];  // [pt][c*16+k]
  __shared__ float                  dk[16][68];      // def_kp(45)+mod(15)

  const int tid  = threadIdx.x;
  const int wave = tid >> 6, lane = tid & 63;
  const int quad = lane >> 4, mm = lane & 15;
  const int base = blockIdx.x * 16;
  _Float16* fTw = fT[wave];
  const floatx4 fz = {0.f, 0.f, 0.f, 0.f};
  const int me = (mm < 15) ? mm : 14;   // row 15 of conv A is discarded

  // ---- stage neighbor displacements + indices ----
  for (int s = tid; s < 640; s += 256) {
    int pt = s / 40, a = s - pt * 40;
    int n = base + pt;
    float px = 1e6f, py = 1e6f, pz = 1e6f;
    int id = 0;
    if (a < 34) {
      id = nidx[n * 34 + a];
      px = support[id * 3 + 0] - query[n * 3 + 0];
      py = support[id * 3 + 1] - query[n * 3 + 1];
      pz = support[id * 3 + 2] - query[n * 3 + 2];
    }
    npx[pt][a] = px; npy[pt][a] = py; npz[pt][a] = pz;
    sidx[pt][a] = (unsigned short)id;
  }
  // ---- zero fT logical chunks 5..7 (a=40..63), per wave, once ----
  {
    int X = ((lane >> 3) ^ (lane & 7)) & 7;
    half8 z8 = {0, 0, 0, 0, 0, 0, 0, 0};
    #pragma unroll
    for (int i = 0; i < 3; ++i)
      *(half8*)(fTw + lane * 64 + (((5 + i) ^ X) << 3)) = z8;
  }
  __syncthreads();

  // ---- gather loads (regs only; no LDS writes) ----
  auto load_g = [&](int pl, uint4* g0, uint4* g1) {
    #pragma unroll
    for (int it = 0; it < 3; ++it) {
      int task = it * 64 + lane;
      if (task < 160) {
        int rp = task >> 3, ch = task & 7;
        int i0 = (int)sidx[pl][2 * rp], i1 = (int)sidx[pl][2 * rp + 1];
        g0[it] = *(const uint4*)(featH + i0 * 64 + ch * 8);
        g1[it] = *(const uint4*)(featH + i1 * 64 + ch * 8);
      }
    }
  };
  // ---- transpose staged regs -> fTw (swizzled) ----
  auto transpose_g = [&](const uint4* g0, const uint4* g1) {
    #pragma unroll
    for (int it = 0; it < 3; ++it) {
      int task = it * 64 + lane;
      if (task < 160) {
        int rp = task >> 3, ch = task & 7;
        const uint* p0 = (const uint*)&g0[it];
        const uint* p1 = (const uint*)&g1[it];
        #pragma unroll
        for (int cc = 0; cc < 8; ++cc) {
          int c = ch * 8 + cc;
          int X = (ch ^ cc) & 7;
          int ap = (2 * rp) ^ (X << 3);
          uint v = __builtin_amdgcn_perm(p1[cc >> 1], p0[cc >> 1],
                                         (cc & 1) ? 0x07060302u : 0x05040100u);
          *(uint*)(fTw + c * 64 + ap) = v;
        }
      }
    }
  };

  // ---- one conv point: influence A-frags + 8 MFMA -> wfh[pl] ----
  auto conv_point = [&](int pl, float kx, float ky, float kz, const float* md) {
    half8 a0, a1;
    #pragma unroll
    for (int j = 0; j < 8; ++j) {
      int a = quad * 8 + j;
      float dx = npx[pl][a] - kx, dy = npy[pl][a] - ky, dz = npz[pl][a] - kz;
      float wv = 1.f - 2.f * sqrtf(dx * dx + dy * dy + dz * dz);
      a0[j] = (_Float16)fmaxf(wv, 0.f);
    }
    if (quad == 0) {
      #pragma unroll
      for (int j = 0; j < 8; ++j) {
        int a = 32 + j;
        float dx = npx[pl][a] - kx, dy = npy[pl][a] - ky, dz = npz[pl][a] - kz;
        float wv = 1.f - 2.f * sqrtf(dx * dx + dy * dy + dz * dz);
        a1[j] = (_Float16)fmaxf(wv, 0.f);
      }
    } else {
      #pragma unroll
      for (int j = 0; j < 8; ++j) a1[j] = (_Float16)0.f;
    }

    floatx4 acc[4];
    #pragma unroll
    for (int ct = 0; ct < 4; ++ct) {
      int c = ct * 16 + mm;
      int X = (((c >> 3) ^ (c & 7)) & 7);
      half8 b = *(const half8*)(fTw + c * 64 + ((quad ^ X) << 3));
      acc[ct] = __builtin_amdgcn_mfma_f32_16x16x32_f16(a0, b, fz, 0, 0, 0);
    }
    #pragma unroll
    for (int ct = 0; ct < 4; ++ct) {
      int c = ct * 16 + mm;
      int X = (((c >> 3) ^ (c & 7)) & 7);
      half8 b = *(const half8*)(fTw + c * 64 + (((4 + quad) ^ X) << 3));
      acc[ct] = __builtin_amdgcn_mfma_f32_16x16x32_f16(a1, b, acc[ct], 0, 0, 0);
    }

    // wfh[pl][c*16 + k], k = quad*4+r : contiguous half4 per ct (b64 writes).
    // k=15 gets finite garbage; weight tables have zero at k=15.
    _Float16* wp = wfh + pl * 1032;
    #pragma unroll
    for (int ct = 0; ct < 4; ++ct) {
      half4 h = {(_Float16)(acc[ct][0] * md[0]), (_Float16)(acc[ct][1] * md[1]),
                 (_Float16)(acc[ct][2] * md[2]), (_Float16)(acc[ct][3] * md[3])};
      *(half4*)(wp + (ct * 16 + mm) * 16 + quad * 4) = h;
    }
  };

  // ---- block GEMM: [16 pts][1024] x bmat[64][1024]^T, wave owns 16 cols ----
  auto gemm = [&](const _Float16* bmat, floatx4& A, floatx4& B) {
    const _Float16* brow = bmat + (wave * 16 + mm) * 1024;
    const _Float16* arow = wfh + mm * 1032;
    A = fz; B = fz;
    #pragma unroll
    for (int k2 = 0; k2 < 32; ++k2) {
      half8 af = *(const half8*)(arow + k2 * 32 + quad * 8);
      half8 bf = *(const half8*)(brow + k2 * 32 + quad * 8);
      if (k2 & 1) B = __builtin_amdgcn_mfma_f32_16x16x32_f16(af, bf, B, 0, 0, 0);
      else        A = __builtin_amdgcn_mfma_f32_16x16x32_f16(af, bf, A, 0, 0, 0);
    }
  };

  uint4 G0[2][3], G1[2][3];

  // ================= conv0 (rigid kernel points) =================
  {
    float k0x = kpts[me * 3 + 0], k0y = kpts[me * 3 + 1], k0z = kpts[me * 3 + 2];
    float one4[4] = {1.f, 1.f, 1.f, 1.f};
    load_g(wave * 4, G0[0], G1[0]);
    #pragma unroll
    for (int pp = 0; pp < 4; ++pp) {
      int pl = wave * 4 + pp;
      if (pp < 3) load_g(pl + 1, G0[(pp + 1) & 1], G1[(pp + 1) & 1]);
      transpose_g(G0[pp & 1], G1[pp & 1]);
      conv_point(pl, k0x, k0y, k0z, one4);
    }
  }
  load_g(wave * 4, G0[0], G1[0]);   // prefetch conv1 p0 under GEMM0
  __syncthreads();

  // ================= GEMM0 -> def_kp + modulations =================
  {
    floatx4 A, B;
    gemm(owt, A, B);
    int d = wave * 16 + mm;
    float bv = (d < 60) ? obias[d] : 0.f;
    float kv = (d < 45) ? kpts[d] : 0.f;
    #pragma unroll
    for (int r = 0; r < 4; ++r) {
      int pt = quad * 4 + r;
      float v = A[r] + B[r] + bv;
      float o = (d < 45) ? (kv + 0.5f * v)            // def_kp = kp + f0*EXTENT
                         : (2.f / (1.f + expf(-v)));  // modulation
      dk[pt][d] = o;
    }
  }
  __syncthreads();   // dk ready; all GEMM0 wfh reads done

  // ================= conv1 (deformed kernel points) =================
  #pragma unroll
  for (int pp = 0; pp < 4; ++pp) {
    int pl = wave * 4 + pp;
    if (pp < 3) load_g(pl + 1, G0[(pp + 1) & 1], G1[(pp + 1) & 1]);
    float kx = dk[pl][me * 3 + 0], ky = dk[pl][me * 3 + 1], kz = dk[pl][me * 3 + 2];
    float md[4];
    #pragma unroll
    for (int r = 0; r < 4; ++r) {
      int k = quad * 4 + r;
      md[r] = (k < 15) ? dk[pl][45 + k] : 1.f;
    }
    transpose_g(G0[pp & 1], G1[pp & 1]);
    conv_point(pl, kx, ky, kz, md);
  }
  __syncthreads();

  // ================= GEMM1 -> x (pre-BN) =================
  {
    floatx4 A, B;
    gemm(wt, A, B);
    int d = wave * 16 + mm;
    #pragma unroll
    for (int r = 0; r < 4; ++r)
      outx[(base + quad * 4 + r) * 64 + d] = A[r] + B[r];
  }
}

// ---------------------------------------------------------------------------
// Per-channel batch stats: stats[0..63]=sum, stats[64..127]=sumsq
// ---------------------------------------------------------------------------
__global__ __launch_bounds__(256) void k_stats(
    const float* __restrict__ x, float* __restrict__ stats)
{
  __shared__ float red[512];
  const int tid = threadIdx.x;
  const int c = tid & 63, g = tid >> 6;
  float s1 = 0.f, s2 = 0.f;
  for (int r = blockIdx.x * 4 + g; r < NPTS; r += 1024) {
    float v = x[r * 64 + c];
    s1 += v; s2 += v * v;
  }
  red[tid] = s1; red[256 + tid] = s2;
  __syncthreads();
  if (tid < 64) {
    s1 = red[tid] + red[tid + 64] + red[tid + 128] + red[tid + 192];
    s2 = red[256 + tid] + red[256 + tid + 64] + red[256 + tid + 128] + red[256 + tid + 192];
    atomicAdd(&stats[c], s1);
    atomicAdd(&stats[64 + c], s2);
  }
}

// ---------------------------------------------------------------------------
// BN (batch stats, biased var, eps=1e-6) + LeakyReLU(0.1), in-place
// ---------------------------------------------------------------------------
__global__ __launch_bounds__(256) void k_norm(
    float* __restrict__ x, const float* __restrict__ stats,
    const float* __restrict__ gamma, const float* __restrict__ beta)
{
  const int i = blockIdx.x * 256 + threadIdx.x;
  float4 v = ((float4*)x)[i];
  const int c0 = (i * 4) & 63;
  float o[4] = {v.x, v.y, v.z, v.w};
  #pragma unroll
  for (int j = 0; j < 4; ++j) {
    int c = c0 + j;
    float mean = stats[c] * (1.f / NPTS);
    float var  = stats[64 + c] * (1.f / NPTS) - mean * mean;
    float s = rsqrtf(var + 1e-6f) * gamma[c];
    float y = (o[j] - mean) * s + beta[c];
    o[j] = (y >= 0.f) ? y : 0.1f * y;
  }
  float4 rv = {o[0], o[1], o[2], o[3]};
  ((float4*)x)[i] = rv;
}

// ---------------------------------------------------------------------------
extern "C" void kernel_launch(void* const* d_in, const int* in_sizes, int n_in,
                              void* d_out, int out_size, void* d_ws, size_t ws_size,
                              hipStream_t stream)
{
  const float* query   = (const float*)d_in[0];
  const float* support = (const float*)d_in[1];
  const int*   nidx    = (const int*)d_in[2];
  const float* feat    = (const float*)d_in[3];
  const float* weight  = (const float*)d_in[4];
  const float* oweight = (const float*)d_in[5];
  const float* obias   = (const float*)d_in[6];
  const float* gamma   = (const float*)d_in[7];
  const float* beta    = (const float*)d_in[8];
  const float* kpts    = (const float*)d_in[9];
  float* x = (float*)d_out;

  char* ws = (char*)d_ws;
  _Float16* featH = (_Float16*)ws;                  // 8,388,608 B
  _Float16* owt   = (_Float16*)(ws + 8388608);      //   131,072 B
  _Float16* wt    = (_Float16*)(ws + 8519680);      //   131,072 B
  float*    stats = (float*)(ws + 8650752);         //       512 B

  hipMemsetAsync(stats, 0, 512, stream);
  k_prep<<<4352, 256, 0, stream>>>(oweight, weight, feat, owt, wt, featH);
  k_fused<<<4096, 256, 0, stream>>>(query, support, nidx, featH, kpts, obias,
                                    owt, wt, x);
  k_stats<<<256, 256, 0, stream>>>(x, stats);
  k_norm<<<4096, 256, 0, stream>>>(x, stats, gamma, beta);
}

// Round 4
// 309.456 us; speedup vs baseline: 1.4802x; 1.2125x over previous
//
#include <hip/hip_runtime.h>
#include <math.h>

#define NPTS 65536

using half8   = __attribute__((ext_vector_type(8))) _Float16;
using half4   = __attribute__((ext_vector_type(4))) _Float16;
using floatx4 = __attribute__((ext_vector_type(4))) float;

// ---------------------------------------------------------------------------
// k_prep: weights -> f16 [64 d][1024 kc'] with kc' = c*16 + k (k=15 row zero);
//         features -> f16 table featH[N][64]
// ---------------------------------------------------------------------------
__global__ __launch_bounds__(256) void k_prep(
    const float* __restrict__ ow, const float* __restrict__ w,
    const float* __restrict__ feat,
    _Float16* __restrict__ owt, _Float16* __restrict__ wt,
    _Float16* __restrict__ featH)
{
  int b = blockIdx.x;
  if (b < 256) {                       // 256*256 == 65536 == 64*1024
    int i = b * 256 + threadIdx.x;
    int d = i >> 10, kc = i & 1023, c = kc >> 4, k = kc & 15;
    owt[i] = (k < 15 && d < 60) ? (_Float16)ow[(k * 64 + c) * 60 + d] : (_Float16)0.f;
    wt[i]  = (k < 15) ? (_Float16)w[(k * 64 + c) * 64 + d] : (_Float16)0.f;
  } else {                             // 4096*256 == 1048576 == N*64/4
    int j = (b - 256) * 256 + threadIdx.x;
    float4 f = ((const float4*)feat)[j];
    half4 h = {(_Float16)f.x, (_Float16)f.y, (_Float16)f.z, (_Float16)f.w};
    ((half4*)featH)[j] = h;
  }
}

// ---------------------------------------------------------------------------
// Fused deformable KPConv. 16 pts/block, 4 waves x 4 pts.
// MFMA covers neighbors 0..31 (fT chunks 0..3, XOR2 swizzle); neighbors 32,33
// via VALU rank-2 (fx2 + ds_bpermute). GEMMs run in 2 half-K phases so wfh is
// halved; ct2/3 accumulators (x mod) held in regs across phase A.
// ---------------------------------------------------------------------------
__global__ __launch_bounds__(256, 3) void k_fused(
    const float* __restrict__ query, const float* __restrict__ support,
    const int* __restrict__ nidx, const _Float16* __restrict__ featH,
    const float* __restrict__ kpts, const float* __restrict__ obias,
    const _Float16* __restrict__ owt, const _Float16* __restrict__ wt,
    float* __restrict__ outx)
{
  __shared__ float                  npx[16][34], npy[16][34], npz[16][34];
  __shared__ unsigned short         sidx[16][34];
  __shared__ __align__(16) _Float16 fT[4][64 * 32];  // per-wave, nbr 0..31
  __shared__ unsigned int           fx2[4][64];      // per-wave, (f32,f33) per c
  __shared__ __align__(16) _Float16 wfh[16 * 520];   // [pt][c'*16+k], half-K
  __shared__ float                  dk[16][64];      // def_kp(45)+mod(15)

  const int tid  = threadIdx.x;
  const int wave = tid >> 6, lane = tid & 63;
  const int quad = lane >> 4, mm = lane & 15;
  const int base = blockIdx.x * 16;
  _Float16* fTw = fT[wave];
  unsigned int* fTw32 = (unsigned int*)fTw;
  unsigned int* fx2w = fx2[wave];
  const floatx4 fz = {0.f, 0.f, 0.f, 0.f};
  const int me = (mm < 15) ? mm : 14;   // row 15 of conv A is discarded

  // ---- stage neighbor displacements + indices (all 34 real, no shadow) ----
  for (int s = tid; s < 544; s += 256) {
    int pt = s / 34, a = s - pt * 34;
    int n = base + pt;
    int id = nidx[n * 34 + a];
    npx[pt][a] = support[id * 3 + 0] - query[n * 3 + 0];
    npy[pt][a] = support[id * 3 + 1] - query[n * 3 + 1];
    npz[pt][a] = support[id * 3 + 2] - query[n * 3 + 2];
    sidx[pt][a] = (unsigned short)id;
  }
  __syncthreads();

  // ---- gather loads (17 row-pairs x 8 chunks = 136 tasks) ----
  auto load_g = [&](int pl, uint4* g0, uint4* g1) {
    #pragma unroll
    for (int it = 0; it < 3; ++it) {
      int task = it * 64 + lane;
      if (task < 136) {
        int rp = task >> 3, ch = task & 7;
        int i0 = (int)sidx[pl][2 * rp], i1 = (int)sidx[pl][2 * rp + 1];
        g0[it] = *(const uint4*)(featH + i0 * 64 + ch * 8);
        g1[it] = *(const uint4*)(featH + i1 * 64 + ch * 8);
      }
    }
  };
  // ---- transpose staged regs -> fTw (rp<16) / fx2w (rp==16) ----
  auto transpose_g = [&](const uint4* g0, const uint4* g1) {
    #pragma unroll
    for (int it = 0; it < 3; ++it) {
      int task = it * 64 + lane;
      if (task < 136) {
        int rp = task >> 3, ch = task & 7;
        const uint* p0 = (const uint*)&g0[it];
        const uint* p1 = (const uint*)&g1[it];
        if (rp < 16) {
          int chunk = rp >> 2, o = rp & 3;
          #pragma unroll
          for (int cc = 0; cc < 8; ++cc) {
            int c  = ch * 8 + cc;
            int pc = chunk ^ ((ch ^ cc) & 3);
            uint v = __builtin_amdgcn_perm(p1[cc >> 1], p0[cc >> 1],
                                           (cc & 1) ? 0x07060302u : 0x05040100u);
            fTw32[c * 16 + pc * 4 + o] = v;
          }
        } else {  // rows 32,33 -> fx2 (lo = f32[c], hi = f33[c])
          #pragma unroll
          for (int cc = 0; cc < 8; ++cc) {
            uint v = __builtin_amdgcn_perm(p1[cc >> 1], p0[cc >> 1],
                                           (cc & 1) ? 0x07060302u : 0x05040100u);
            fx2w[ch * 8 + cc] = v;
          }
        }
      }
    }
  };

  // ---- one conv point: 4 MFMA (nbr 0..31) + rank-2 (nbr 32,33), x mod.
  //      writes ct0/1 to wfh, returns ct2/3 in hold[2] ----
  auto conv_point = [&](int pl, float kx, float ky, float kz, const float* md,
                        floatx4* hold) {
    half8 a0;
    #pragma unroll
    for (int j = 0; j < 8; ++j) {
      int a = quad * 8 + j;
      float dx = npx[pl][a] - kx, dy = npy[pl][a] - ky, dz = npz[pl][a] - kz;
      float wv = 1.f - 2.f * sqrtf(dx * dx + dy * dy + dz * dz);
      a0[j] = (_Float16)fmaxf(wv, 0.f);
    }
    // rank-2 influence at kp=me, then redistribute to k=quad*4+r via bpermute
    float w32, w33;
    {
      float dx = npx[pl][32] - kx, dy = npy[pl][32] - ky, dz = npz[pl][32] - kz;
      w32 = fmaxf(1.f - 2.f * sqrtf(dx * dx + dy * dy + dz * dz), 0.f);
      dx = npx[pl][33] - kx; dy = npy[pl][33] - ky; dz = npz[pl][33] - kz;
      w33 = fmaxf(1.f - 2.f * sqrtf(dx * dx + dy * dy + dz * dz), 0.f);
    }
    float w32r[4], w33r[4];
    #pragma unroll
    for (int r = 0; r < 4; ++r) {
      int src = (quad * 4 + r) << 2;
      w32r[r] = __int_as_float(__builtin_amdgcn_ds_bpermute(src, __float_as_int(w32)));
      w33r[r] = __int_as_float(__builtin_amdgcn_ds_bpermute(src, __float_as_int(w33)));
    }

    floatx4 acc[4];
    #pragma unroll
    for (int ct = 0; ct < 4; ++ct) {
      int c  = ct * 16 + mm;
      int pc = quad ^ (((c >> 3) ^ c) & 3);
      half8 b = *(const half8*)(fTw + c * 32 + pc * 8);
      acc[ct] = __builtin_amdgcn_mfma_f32_16x16x32_f16(a0, b, fz, 0, 0, 0);
    }
    #pragma unroll
    for (int ct = 0; ct < 4; ++ct) {
      int c = ct * 16 + mm;
      uint fp = fx2w[c];
      _Float16 lo = __builtin_bit_cast(_Float16, (unsigned short)(fp & 0xffffu));
      _Float16 hi = __builtin_bit_cast(_Float16, (unsigned short)(fp >> 16));
      float flo = (float)lo, fhi = (float)hi;
      #pragma unroll
      for (int r = 0; r < 4; ++r)
        acc[ct][r] = (acc[ct][r] + w32r[r] * flo + w33r[r] * fhi) * md[r];
    }

    _Float16* wp = wfh + pl * 520;
    #pragma unroll
    for (int ct = 0; ct < 2; ++ct) {
      half4 h = {(_Float16)acc[ct][0], (_Float16)acc[ct][1],
                 (_Float16)acc[ct][2], (_Float16)acc[ct][3]};
      *(half4*)(wp + (ct * 16 + mm) * 16 + quad * 4) = h;
    }
    hold[0] = acc[2]; hold[1] = acc[3];
  };

  // ---- write held ct2/3 accs into wfh (phase B) ----
  auto write_hold = [&](const floatx4 (*hold)[2]) {
    #pragma unroll
    for (int pp = 0; pp < 4; ++pp) {
      _Float16* wp = wfh + (wave * 4 + pp) * 520;
      #pragma unroll
      for (int ct = 0; ct < 2; ++ct) {
        const floatx4& a = hold[pp][ct];
        half4 h = {(_Float16)a[0], (_Float16)a[1], (_Float16)a[2], (_Float16)a[3]};
        *(half4*)(wp + (ct * 16 + mm) * 16 + quad * 4) = h;
      }
    }
  };

  // ---- half-K GEMM: 16 k-steps vs bmat rows [64][1024], offset 0 or 512 ----
  auto gemm_half = [&](const _Float16* bmat, int koff, floatx4& A, floatx4& B) {
    const _Float16* brow = bmat + (wave * 16 + mm) * 1024 + koff;
    const _Float16* arow = wfh + mm * 520;
    #pragma unroll
    for (int k2 = 0; k2 < 16; ++k2) {
      half8 af = *(const half8*)(arow + k2 * 32 + quad * 8);
      half8 bf = *(const half8*)(brow + k2 * 32 + quad * 8);
      if (k2 & 1) B = __builtin_amdgcn_mfma_f32_16x16x32_f16(af, bf, B, 0, 0, 0);
      else        A = __builtin_amdgcn_mfma_f32_16x16x32_f16(af, bf, A, 0, 0, 0);
    }
  };

  uint4 G0[2][3], G1[2][3];
  floatx4 hold[4][2];
  const float one4[4] = {1.f, 1.f, 1.f, 1.f};

  // ================= conv0 (rigid kernel points) =================
  {
    float k0x = kpts[me * 3 + 0], k0y = kpts[me * 3 + 1], k0z = kpts[me * 3 + 2];
    load_g(wave * 4, G0[0], G1[0]);
    #pragma unroll
    for (int pp = 0; pp < 4; ++pp) {
      int pl = wave * 4 + pp;
      if (pp < 3) load_g(pl + 1, G0[(pp + 1) & 1], G1[(pp + 1) & 1]);
      transpose_g(G0[pp & 1], G1[pp & 1]);
      conv_point(pl, k0x, k0y, k0z, one4, hold[pp]);
    }
  }
  load_g(wave * 4, G0[0], G1[0]);   // prefetch conv1 p0 under GEMM0
  __syncthreads();

  // ================= GEMM0 (2 phases) -> def_kp + modulations =================
  {
    floatx4 A = fz, B = fz;
    gemm_half(owt, 0, A, B);
    __syncthreads();
    write_hold(hold);
    __syncthreads();
    gemm_half(owt, 512, A, B);
    int d = wave * 16 + mm;
    float bv = (d < 60) ? obias[d] : 0.f;
    float kv = (d < 45) ? kpts[d] : 0.f;
    #pragma unroll
    for (int r = 0; r < 4; ++r) {
      int pt = quad * 4 + r;
      float v = A[r] + B[r] + bv;
      float o = (d < 45) ? (kv + 0.5f * v)            // def_kp = kp + f0*EXTENT
                         : (2.f / (1.f + expf(-v)));  // modulation
      dk[pt][d] = o;
    }
  }
  __syncthreads();   // dk ready; GEMM0 wfh reads done

  // ================= conv1 (deformed kernel points) =================
  #pragma unroll
  for (int pp = 0; pp < 4; ++pp) {
    int pl = wave * 4 + pp;
    if (pp < 3) load_g(pl + 1, G0[(pp + 1) & 1], G1[(pp + 1) & 1]);
    float kx = dk[pl][me * 3 + 0], ky = dk[pl][me * 3 + 1], kz = dk[pl][me * 3 + 2];
    float md[4];
    #pragma unroll
    for (int r = 0; r < 4; ++r) {
      int k = quad * 4 + r;
      md[r] = (k < 15) ? dk[pl][45 + k] : 1.f;
    }
    transpose_g(G0[pp & 1], G1[pp & 1]);
    conv_point(pl, kx, ky, kz, md, hold[pp]);
  }
  __syncthreads();

  // ================= GEMM1 (2 phases) -> x (pre-BN) =================
  {
    floatx4 A = fz, B = fz;
    gemm_half(wt, 0, A, B);
    __syncthreads();
    write_hold(hold);
    __syncthreads();
    gemm_half(wt, 512, A, B);
    int d = wave * 16 + mm;
    #pragma unroll
    for (int r = 0; r < 4; ++r)
      outx[(base + quad * 4 + r) * 64 + d] = A[r] + B[r];
  }
}

// ---------------------------------------------------------------------------
// Per-channel batch stats: stats[0..63]=sum, stats[64..127]=sumsq
// ---------------------------------------------------------------------------
__global__ __launch_bounds__(256) void k_stats(
    const float* __restrict__ x, float* __restrict__ stats)
{
  __shared__ float red[512];
  const int tid = threadIdx.x;
  const int c = tid & 63, g = tid >> 6;
  float s1 = 0.f, s2 = 0.f;
  for (int r = blockIdx.x * 4 + g; r < NPTS; r += 1024) {
    float v = x[r * 64 + c];
    s1 += v; s2 += v * v;
  }
  red[tid] = s1; red[256 + tid] = s2;
  __syncthreads();
  if (tid < 64) {
    s1 = red[tid] + red[tid + 64] + red[tid + 128] + red[tid + 192];
    s2 = red[256 + tid] + red[256 + tid + 64] + red[256 + tid + 128] + red[256 + tid + 192];
    atomicAdd(&stats[c], s1);
    atomicAdd(&stats[64 + c], s2);
  }
}

// ---------------------------------------------------------------------------
// BN (batch stats, biased var, eps=1e-6) + LeakyReLU(0.1), in-place
// ---------------------------------------------------------------------------
__global__ __launch_bounds__(256) void k_norm(
    float* __restrict__ x, const float* __restrict__ stats,
    const float* __restrict__ gamma, const float* __restrict__ beta)
{
  const int i = blockIdx.x * 256 + threadIdx.x;
  float4 v = ((float4*)x)[i];
  const int c0 = (i * 4) & 63;
  float o[4] = {v.x, v.y, v.z, v.w};
  #pragma unroll
  for (int j = 0; j < 4; ++j) {
    int c = c0 + j;
    float mean = stats[c] * (1.f / NPTS);
    float var  = stats[64 + c] * (1.f / NPTS) - mean * mean;
    float s = rsqrtf(var + 1e-6f) * gamma[c];
    float y = (o[j] - mean) * s + beta[c];
    o[j] = (y >= 0.f) ? y : 0.1f * y;
  }
  float4 rv = {o[0], o[1], o[2], o[3]};
  ((float4*)x)[i] = rv;
}

// ---------------------------------------------------------------------------
extern "C" void kernel_launch(void* const* d_in, const int* in_sizes, int n_in,
                              void* d_out, int out_size, void* d_ws, size_t ws_size,
                              hipStream_t stream)
{
  const float* query   = (const float*)d_in[0];
  const float* support = (const float*)d_in[1];
  const int*   nidx    = (const int*)d_in[2];
  const float* feat    = (const float*)d_in[3];
  const float* weight  = (const float*)d_in[4];
  const float* oweight = (const float*)d_in[5];
  const float* obias   = (const float*)d_in[6];
  const float* gamma   = (const float*)d_in[7];
  const float* beta    = (const float*)d_in[8];
  const float* kpts    = (const float*)d_in[9];
  float* x = (float*)d_out;

  char* ws = (char*)d_ws;
  _Float16* featH = (_Float16*)ws;                  // 8,388,608 B
  _Float16* owt   = (_Float16*)(ws + 8388608);      //   131,072 B
  _Float16* wt    = (_Float16*)(ws + 8519680);      //   131,072 B
  float*    stats = (float*)(ws + 8650752);         //       512 B

  hipMemsetAsync(stats, 0, 512, stream);
  k_prep<<<4352, 256, 0, stream>>>(oweight, weight, feat, owt, wt, featH);
  k_fused<<<4096, 256, 0, stream>>>(query, support, nidx, featH, kpts, obias,
                                    owt, wt, x);
  k_stats<<<256, 256, 0, stream>>>(x, stats);
  k_norm<<<4096, 256, 0, stream>>>(x, stats, gamma, beta);
}